// Round 1
// baseline (180.508 us; speedup 1.0000x reference)
//
#include <hip/hip_runtime.h>
#include <math.h>

#define BB 2
#define NN 2048
#define NP1 2049
#define DM 128
#define NH 8
#define DK 16
#define RWIN 4
#define GRID_W 64
#define CELLS (GRID_W * GRID_W)
#define TOTC (BB * CELLS) /* 8192 */

// ---------------- bucket build ----------------

__global__ __launch_bounds__(256) void hist_kernel(const int* __restrict__ positions,
                                                   const float* __restrict__ alive,
                                                   int* __restrict__ counts) {
    int idx = blockIdx.x * 256 + threadIdx.x; // over B*N
    if (idx >= BB * NN) return;
    if (alive[idx] > 0.5f) {
        int b = idx / NN;
        int px = positions[idx * 2 + 0];
        int py = positions[idx * 2 + 1];
        atomicAdd(&counts[b * CELLS + px * GRID_W + py], 1);
    }
}

__global__ __launch_bounds__(256) void scan_kernel(const int* __restrict__ counts,
                                                   int* __restrict__ start,
                                                   int* __restrict__ cursor) {
    __shared__ int psum[257];
    const int tid = threadIdx.x;
    const int PER = TOTC / 256; // 32
    int local[PER];
    int s = 0;
#pragma unroll
    for (int u = 0; u < PER; ++u) { local[u] = counts[tid * PER + u]; s += local[u]; }
    psum[tid + 1] = s;
    __syncthreads();
    if (tid == 0) {
        psum[0] = 0;
        for (int t = 1; t <= 256; ++t) psum[t] += psum[t - 1];
    }
    __syncthreads();
    int run = psum[tid];
#pragma unroll
    for (int u = 0; u < PER; ++u) {
        start[tid * PER + u] = run;
        cursor[tid * PER + u] = run;
        run += local[u];
    }
    if (tid == 255) start[TOTC] = run;
}

__global__ __launch_bounds__(256) void scatter_kernel(const int* __restrict__ positions,
                                                      const float* __restrict__ alive,
                                                      int* __restrict__ cursor,
                                                      int* __restrict__ bucket) {
    int idx = blockIdx.x * 256 + threadIdx.x;
    if (idx >= BB * NN) return;
    if (alive[idx] > 0.5f) {
        int b = idx / NN;
        int n = idx % NN;
        int px = positions[idx * 2 + 0];
        int py = positions[idx * 2 + 1];
        int slot = atomicAdd(&cursor[b * CELLS + px * GRID_W + py], 1);
        bucket[slot] = n | (px << 16) | (py << 24);
    }
}

// ---------------- QKV projection: rows of [z;patch] @ {Wq,Wk,Wv} ----------------
// 8 rows per block, 128 threads (one output column each).

__global__ __launch_bounds__(128) void qkv_kernel(
    const float* __restrict__ z, const float* __restrict__ patch,
    const float* __restrict__ Wq, const float* __restrict__ bq,
    const float* __restrict__ Wk, const float* __restrict__ bk,
    const float* __restrict__ Wv, const float* __restrict__ bv,
    float* __restrict__ q, float* __restrict__ k, float* __restrict__ v) {
    __shared__ float zrow[8][DM];
    const int tid = threadIdx.x;
    const int r0 = blockIdx.x * 8;
    const int NROWS = BB * NP1;
#pragma unroll
    for (int r = 0; r < 8; ++r) {
        int row = r0 + r;
        float val = 0.f;
        if (row < NROWS) {
            int b = row / NP1, ti = row % NP1;
            const float* src = (ti < NN) ? (z + ((size_t)b * NN + ti) * DM)
                                         : (patch + (size_t)b * DM);
            val = src[tid];
        }
        zrow[r][tid] = val;
    }
    __syncthreads();
    float aq[8] = {0, 0, 0, 0, 0, 0, 0, 0};
    float ak[8] = {0, 0, 0, 0, 0, 0, 0, 0};
    float av[8] = {0, 0, 0, 0, 0, 0, 0, 0};
    for (int kk = 0; kk < DM; ++kk) {
        float wq = Wq[kk * DM + tid];
        float wk = Wk[kk * DM + tid];
        float wv = Wv[kk * DM + tid];
#pragma unroll
        for (int r = 0; r < 8; ++r) {
            float zz = zrow[r][kk];
            aq[r] = fmaf(zz, wq, aq[r]);
            ak[r] = fmaf(zz, wk, ak[r]);
            av[r] = fmaf(zz, wv, av[r]);
        }
    }
    const float bqv = bq[tid], bkv = bk[tid], bvv = bv[tid];
#pragma unroll
    for (int r = 0; r < 8; ++r) {
        int row = r0 + r;
        if (row < NROWS) {
            int b = row / NP1, ti = row % NP1;
            size_t kvoff = ((size_t)b * NP1 + ti) * DM + tid;
            k[kvoff] = ak[r] + bkv;
            v[kvoff] = av[r] + bvv;
            if (ti < NN) q[((size_t)b * NN + ti) * DM + tid] = aq[r] + bqv;
        }
    }
}

// ---------------- sparse local attention, online softmax ----------------
// One block per (b,i) query. 128 threads = 8 heads x 16 lanes.

__global__ __launch_bounds__(128) void attn_kernel(
    const float* __restrict__ q, const float* __restrict__ k, const float* __restrict__ v,
    const int* __restrict__ positions, const float* __restrict__ alive,
    const int* __restrict__ start, const int* __restrict__ bucket,
    const float* __restrict__ rel_bias, float* __restrict__ attn_out) {
    const int tid = threadIdx.x;
    const int bi = blockIdx.x; // b*N + i
    const int b = bi / NN, i = bi % NN;
    float* orow = attn_out + (size_t)bi * DM;
    if (alive[bi] <= 0.5f) { orow[tid] = 0.f; return; }

    __shared__ float sbias[NH * 81];
    for (int t = tid; t < NH * 81; t += 128) sbias[t] = rel_bias[t];
    __syncthreads();

    const int pix = positions[bi * 2 + 0];
    const int piy = positions[bi * 2 + 1];
    const float qv = q[(size_t)bi * DM + tid] * 0.25f; // 1/sqrt(16)
    const int h = tid >> 4;
    const float* kb = k + (size_t)b * NP1 * DM;
    const float* vb = v + (size_t)b * NP1 * DM;

    // patch column first (always allowed, no bias)
    float dot = qv * kb[(size_t)NN * DM + tid];
#pragma unroll
    for (int off = 8; off; off >>= 1) dot += __shfl_xor(dot, off, 16);
    float m = dot;
    float l = 1.f;
    float o = vb[(size_t)NN * DM + tid];

    const int x0 = (pix - RWIN < 0) ? 0 : pix - RWIN;
    const int x1 = (pix + RWIN > GRID_W - 1) ? GRID_W - 1 : pix + RWIN;
    const int y0 = (piy - RWIN < 0) ? 0 : piy - RWIN;
    const int y1 = (piy + RWIN > GRID_W - 1) ? GRID_W - 1 : piy + RWIN;

    for (int x = x0; x <= x1; ++x) {
        int cbase = b * CELLS + x * GRID_W;
        int s = start[cbase + y0];
        int e = start[cbase + y1 + 1]; // y-cells are contiguous in the flattening
        for (int t = s; t < e; ++t) {
            int packed = bucket[t];
            int j = packed & 0xFFFF;
            if (j == i) continue;
            float d2 = qv * kb[(size_t)j * DM + tid];
#pragma unroll
            for (int off = 8; off; off >>= 1) d2 += __shfl_xor(d2, off, 16);
            int pjx = (packed >> 16) & 0xFF;
            int pjy = (packed >> 24) & 0xFF;
            float bias = sbias[h * 81 + (pjx - pix + RWIN) * 9 + (pjy - piy + RWIN)];
            float lg = d2 + bias;
            float mn = fmaxf(m, lg);
            float al = __expf(m - mn);
            float p = __expf(lg - mn);
            l = l * al + p;
            o = fmaf(o, al, p * vb[(size_t)j * DM + tid]);
            m = mn;
        }
    }
    orow[tid] = o / l;
}

// ---------------- output projection ----------------

__global__ __launch_bounds__(128) void out_kernel(
    const float* __restrict__ attn_out, const float* __restrict__ Wo,
    const float* __restrict__ bo, const float* __restrict__ alive,
    float* __restrict__ out) {
    __shared__ float arow[8][DM];
    __shared__ float am[8];
    const int tid = threadIdx.x;
    const int r0 = blockIdx.x * 8; // B*N = 4096 divides by 8 exactly
#pragma unroll
    for (int r = 0; r < 8; ++r) arow[r][tid] = attn_out[(size_t)(r0 + r) * DM + tid];
    if (tid < 8) am[tid] = alive[r0 + tid];
    __syncthreads();
    float acc[8] = {0, 0, 0, 0, 0, 0, 0, 0};
    for (int kk = 0; kk < DM; ++kk) {
        float w = Wo[kk * DM + tid];
#pragma unroll
        for (int r = 0; r < 8; ++r) acc[r] = fmaf(arow[r][kk], w, acc[r]);
    }
    const float bov = bo[tid];
#pragma unroll
    for (int r = 0; r < 8; ++r)
        out[(size_t)(r0 + r) * DM + tid] = (acc[r] + bov) * am[r];
}

extern "C" void kernel_launch(void* const* d_in, const int* in_sizes, int n_in,
                              void* d_out, int out_size, void* d_ws, size_t ws_size,
                              hipStream_t stream) {
    const float* z         = (const float*)d_in[0];
    const float* patch     = (const float*)d_in[1];
    const int*   positions = (const int*)d_in[2];
    const float* alive     = (const float*)d_in[3];
    const float* Wq        = (const float*)d_in[4];
    const float* bq        = (const float*)d_in[5];
    const float* Wk        = (const float*)d_in[6];
    const float* bk        = (const float*)d_in[7];
    const float* Wv        = (const float*)d_in[8];
    const float* bv        = (const float*)d_in[9];
    const float* Wo        = (const float*)d_in[10];
    const float* bo        = (const float*)d_in[11];
    const float* rel_bias  = (const float*)d_in[12];
    float* out = (float*)d_out;

    char* ws = (char*)d_ws;
    size_t off = 0;
    auto alloc = [&](size_t bytes) -> void* {
        void* p = ws + off;
        off += (bytes + 255) & ~(size_t)255;
        return p;
    };
    float* q      = (float*)alloc((size_t)BB * NN * DM * 4);
    float* k      = (float*)alloc((size_t)BB * NP1 * DM * 4);
    float* v      = (float*)alloc((size_t)BB * NP1 * DM * 4);
    float* attn   = (float*)alloc((size_t)BB * NN * DM * 4);
    int*   counts = (int*)alloc((size_t)TOTC * 4);
    int*   start  = (int*)alloc((size_t)(TOTC + 1) * 4);
    int*   cursor = (int*)alloc((size_t)TOTC * 4);
    int*   bucket = (int*)alloc((size_t)BB * NN * 4);

    hipMemsetAsync(counts, 0, (size_t)TOTC * 4, stream);
    hist_kernel<<<(BB * NN + 255) / 256, 256, 0, stream>>>(positions, alive, counts);
    scan_kernel<<<1, 256, 0, stream>>>(counts, start, cursor);
    scatter_kernel<<<(BB * NN + 255) / 256, 256, 0, stream>>>(positions, alive, cursor, bucket);
    qkv_kernel<<<(BB * NP1 + 7) / 8, 128, 0, stream>>>(z, patch, Wq, bq, Wk, bk, Wv, bv, q, k, v);
    attn_kernel<<<BB * NN, 128, 0, stream>>>(q, k, v, positions, alive, start, bucket, rel_bias, attn);
    out_kernel<<<(BB * NN) / 8, 128, 0, stream>>>(attn, Wo, bo, alive, out);
}

// Round 2
// 143.519 us; speedup vs baseline: 1.2577x; 1.2577x over previous
//
#include <hip/hip_runtime.h>
#include <math.h>

#define BB 2
#define NN 2048
#define NP1 2049
#define DM 128
#define NH 8
#define DK 16
#define RWIN 4
#define GRID_W 64
#define CELLS (GRID_W * GRID_W)
#define TOTC (BB * CELLS) /* 8192 */

// ---------------- bucket build ----------------

__global__ __launch_bounds__(256) void hist_kernel(const int* __restrict__ positions,
                                                   const float* __restrict__ alive,
                                                   int* __restrict__ counts) {
    int idx = blockIdx.x * 256 + threadIdx.x; // over B*N
    if (idx >= BB * NN) return;
    if (alive[idx] > 0.5f) {
        int b = idx / NN;
        int px = positions[idx * 2 + 0];
        int py = positions[idx * 2 + 1];
        atomicAdd(&counts[b * CELLS + px * GRID_W + py], 1);
    }
}

__global__ __launch_bounds__(256) void scan_kernel(const int* __restrict__ counts,
                                                   int* __restrict__ start,
                                                   int* __restrict__ cursor) {
    __shared__ int psum[257];
    const int tid = threadIdx.x;
    const int PER = TOTC / 256; // 32
    int local[PER];
    int s = 0;
#pragma unroll
    for (int u = 0; u < PER; ++u) { local[u] = counts[tid * PER + u]; s += local[u]; }
    psum[tid + 1] = s;
    __syncthreads();
    if (tid == 0) {
        psum[0] = 0;
        for (int t = 1; t <= 256; ++t) psum[t] += psum[t - 1];
    }
    __syncthreads();
    int run = psum[tid];
#pragma unroll
    for (int u = 0; u < PER; ++u) {
        start[tid * PER + u] = run;
        cursor[tid * PER + u] = run;
        run += local[u];
    }
    if (tid == 255) start[TOTC] = run;
}

__global__ __launch_bounds__(256) void scatter_kernel(const int* __restrict__ positions,
                                                      const float* __restrict__ alive,
                                                      int* __restrict__ cursor,
                                                      int* __restrict__ bucket) {
    int idx = blockIdx.x * 256 + threadIdx.x;
    if (idx >= BB * NN) return;
    if (alive[idx] > 0.5f) {
        int b = idx / NN;
        int n = idx % NN;
        int px = positions[idx * 2 + 0];
        int py = positions[idx * 2 + 1];
        int slot = atomicAdd(&cursor[b * CELLS + px * GRID_W + py], 1);
        bucket[slot] = n | (px << 16) | (py << 24);
    }
}

// ---------------- QKV projection ----------------
// 384 threads = 3 matrices x 128 cols (matrix select is wave-uniform).
// 4 rows per block -> grid 1025, ~24 waves/CU. Unroll-8 K-loop for MLP.

#define QKV_ROWS 4

__global__ __launch_bounds__(384) void qkv_kernel(
    const float* __restrict__ z, const float* __restrict__ patch,
    const float* __restrict__ Wq, const float* __restrict__ bq,
    const float* __restrict__ Wk, const float* __restrict__ bk,
    const float* __restrict__ Wv, const float* __restrict__ bv,
    float* __restrict__ q, float* __restrict__ k, float* __restrict__ v) {
    __shared__ float zrow[QKV_ROWS][DM];
    const int tid = threadIdx.x;
    const int col = tid & 127;
    const int mat = tid >> 7; // 0=q 1=k 2=v, wave-uniform
    const int r0 = blockIdx.x * QKV_ROWS;
    const int NROWS = BB * NP1;

    for (int t = tid; t < QKV_ROWS * DM; t += 384) {
        int r = t >> 7, c = t & 127;
        int row = r0 + r;
        float val = 0.f;
        if (row < NROWS) {
            int b = row / NP1, ti = row % NP1;
            val = (ti < NN) ? z[((size_t)b * NN + ti) * DM + c]
                            : patch[(size_t)b * DM + c];
        }
        zrow[r][c] = val;
    }
    __syncthreads();

    const float* W    = (mat == 0) ? Wq : (mat == 1) ? Wk : Wv;
    const float* bias = (mat == 0) ? bq : (mat == 1) ? bk : bv;

    float acc[QKV_ROWS] = {0, 0, 0, 0};
#pragma unroll 8
    for (int kk = 0; kk < DM; ++kk) {
        float w = W[kk * DM + col];
#pragma unroll
        for (int r = 0; r < QKV_ROWS; ++r) acc[r] = fmaf(zrow[r][kk], w, acc[r]);
    }
    const float bv_ = bias[col];
#pragma unroll
    for (int r = 0; r < QKV_ROWS; ++r) {
        int row = r0 + r;
        if (row >= NROWS) break;
        int b = row / NP1, ti = row % NP1;
        float val = acc[r] + bv_;
        if (mat == 0) {
            if (ti < NN) q[((size_t)b * NN + ti) * DM + col] = val;
        } else if (mat == 1) {
            k[((size_t)b * NP1 + ti) * DM + col] = val;
        } else {
            v[((size_t)b * NP1 + ti) * DM + col] = val;
        }
    }
}

// ---------------- sparse local attention, online softmax ----------------
// One block per (b,i) query. 128 threads = 8 heads x 16 lanes.

__global__ __launch_bounds__(128) void attn_kernel(
    const float* __restrict__ q, const float* __restrict__ k, const float* __restrict__ v,
    const int* __restrict__ positions, const float* __restrict__ alive,
    const int* __restrict__ start, const int* __restrict__ bucket,
    const float* __restrict__ rel_bias, float* __restrict__ attn_out) {
    const int tid = threadIdx.x;
    const int bi = blockIdx.x; // b*N + i
    const int b = bi / NN, i = bi % NN;
    float* orow = attn_out + (size_t)bi * DM;
    if (alive[bi] <= 0.5f) { orow[tid] = 0.f; return; }

    __shared__ float sbias[NH * 81];
    for (int t = tid; t < NH * 81; t += 128) sbias[t] = rel_bias[t];
    __syncthreads();

    const int pix = positions[bi * 2 + 0];
    const int piy = positions[bi * 2 + 1];
    const float qv = q[(size_t)bi * DM + tid] * 0.25f; // 1/sqrt(16)
    const int h = tid >> 4;
    const float* kb = k + (size_t)b * NP1 * DM;
    const float* vb = v + (size_t)b * NP1 * DM;

    // patch column first (always allowed, no bias)
    float dot = qv * kb[(size_t)NN * DM + tid];
#pragma unroll
    for (int off = 8; off; off >>= 1) dot += __shfl_xor(dot, off, 16);
    float m = dot;
    float l = 1.f;
    float o = vb[(size_t)NN * DM + tid];

    const int x0 = (pix - RWIN < 0) ? 0 : pix - RWIN;
    const int x1 = (pix + RWIN > GRID_W - 1) ? GRID_W - 1 : pix + RWIN;
    const int y0 = (piy - RWIN < 0) ? 0 : piy - RWIN;
    const int y1 = (piy + RWIN > GRID_W - 1) ? GRID_W - 1 : piy + RWIN;

    for (int x = x0; x <= x1; ++x) {
        int cbase = b * CELLS + x * GRID_W;
        int s = start[cbase + y0];
        int e = start[cbase + y1 + 1]; // y-cells are contiguous in the flattening
        for (int t = s; t < e; ++t) {
            int packed = bucket[t];
            int j = packed & 0xFFFF;
            if (j == i) continue;
            float d2 = qv * kb[(size_t)j * DM + tid];
#pragma unroll
            for (int off = 8; off; off >>= 1) d2 += __shfl_xor(d2, off, 16);
            int pjx = (packed >> 16) & 0xFF;
            int pjy = (packed >> 24) & 0xFF;
            float bias = sbias[h * 81 + (pjx - pix + RWIN) * 9 + (pjy - piy + RWIN)];
            float lg = d2 + bias;
            float mn = fmaxf(m, lg);
            float al = __expf(m - mn);
            float p = __expf(lg - mn);
            l = l * al + p;
            o = fmaf(o, al, p * vb[(size_t)j * DM + tid]);
            m = mn;
        }
    }
    orow[tid] = o / l;
}

// ---------------- output projection ----------------
// 4 rows/block -> grid 1024. Unroll-8 K-loop.

#define OUT_ROWS 4

__global__ __launch_bounds__(128) void out_kernel(
    const float* __restrict__ attn_out, const float* __restrict__ Wo,
    const float* __restrict__ bo, const float* __restrict__ alive,
    float* __restrict__ out) {
    __shared__ float arow[OUT_ROWS][DM];
    __shared__ float am[OUT_ROWS];
    const int tid = threadIdx.x;
    const int r0 = blockIdx.x * OUT_ROWS; // B*N = 4096 divides by 4 exactly
#pragma unroll
    for (int r = 0; r < OUT_ROWS; ++r) arow[r][tid] = attn_out[(size_t)(r0 + r) * DM + tid];
    if (tid < OUT_ROWS) am[tid] = alive[r0 + tid];
    __syncthreads();
    float acc[OUT_ROWS] = {0, 0, 0, 0};
#pragma unroll 8
    for (int kk = 0; kk < DM; ++kk) {
        float w = Wo[kk * DM + tid];
#pragma unroll
        for (int r = 0; r < OUT_ROWS; ++r) acc[r] = fmaf(arow[r][kk], w, acc[r]);
    }
    const float bov = bo[tid];
#pragma unroll
    for (int r = 0; r < OUT_ROWS; ++r)
        out[(size_t)(r0 + r) * DM + tid] = (acc[r] + bov) * am[r];
}

extern "C" void kernel_launch(void* const* d_in, const int* in_sizes, int n_in,
                              void* d_out, int out_size, void* d_ws, size_t ws_size,
                              hipStream_t stream) {
    const float* z         = (const float*)d_in[0];
    const float* patch     = (const float*)d_in[1];
    const int*   positions = (const int*)d_in[2];
    const float* alive     = (const float*)d_in[3];
    const float* Wq        = (const float*)d_in[4];
    const float* bq        = (const float*)d_in[5];
    const float* Wk        = (const float*)d_in[6];
    const float* bk        = (const float*)d_in[7];
    const float* Wv        = (const float*)d_in[8];
    const float* bv        = (const float*)d_in[9];
    const float* Wo        = (const float*)d_in[10];
    const float* bo        = (const float*)d_in[11];
    const float* rel_bias  = (const float*)d_in[12];
    float* out = (float*)d_out;

    char* ws = (char*)d_ws;
    size_t off = 0;
    auto alloc = [&](size_t bytes) -> void* {
        void* p = ws + off;
        off += (bytes + 255) & ~(size_t)255;
        return p;
    };
    float* q      = (float*)alloc((size_t)BB * NN * DM * 4);
    float* k      = (float*)alloc((size_t)BB * NP1 * DM * 4);
    float* v      = (float*)alloc((size_t)BB * NP1 * DM * 4);
    float* attn   = (float*)alloc((size_t)BB * NN * DM * 4);
    int*   counts = (int*)alloc((size_t)TOTC * 4);
    int*   start  = (int*)alloc((size_t)(TOTC + 1) * 4);
    int*   cursor = (int*)alloc((size_t)TOTC * 4);
    int*   bucket = (int*)alloc((size_t)BB * NN * 4);

    hipMemsetAsync(counts, 0, (size_t)TOTC * 4, stream);
    hist_kernel<<<(BB * NN + 255) / 256, 256, 0, stream>>>(positions, alive, counts);
    scan_kernel<<<1, 256, 0, stream>>>(counts, start, cursor);
    scatter_kernel<<<(BB * NN + 255) / 256, 256, 0, stream>>>(positions, alive, cursor, bucket);
    qkv_kernel<<<(BB * NP1 + QKV_ROWS - 1) / QKV_ROWS, 384, 0, stream>>>(z, patch, Wq, bq, Wk, bk, Wv, bv, q, k, v);
    attn_kernel<<<BB * NN, 128, 0, stream>>>(q, k, v, positions, alive, start, bucket, rel_bias, attn);
    out_kernel<<<(BB * NN) / OUT_ROWS, 128, 0, stream>>>(attn, Wo, bo, alive, out);
}